// Round 10
// baseline (196.519 us; speedup 1.0000x reference)
//
#include <hip/hip_runtime.h>

// y[b,o,p] = sum_c wproj[o,c] * illu[b,c,p] * (sum_i wmix[c,i]*x[b,i,p])
// (attention collapses: DIM==HEADS==64 => softmax over singleton == 1.0;
//  0.6/0.4 output mix commutes onto the weights: wmix = .6*wvs + .4*wvt)
//
// R16: per-lane load WIDTH isolation. R15 null (FETCH/dur unchanged) killed
// the L3-residency theory. Remaining invariant across ALL ten variants:
// x/illu loaded as 4B/lane scalar dwords (window=32px locks lanes to
// 4 rows x 16px). Guide G13/m18/m146: scalar-width loads cap device BW at
// ~2.35 TB/s; 16B/lane reaches 4.9-6.3 TB/s (m13 float4 copy = 6.29).
// Our clean-traffic pin of 1.9-2.0 TB/s == the scalar ceiling.
// Fix: 128-px tiles; x/illu loaded dwordx4 (16B/lane, m13's exact pattern:
// one inst = 2 channel-rows x 512B contiguous = 1KB), staged through LDS:
//   - x -> XT[p][c] bf16 transpose (fragments/MFMA/gate/u'-bounce and the
//     paired-half-line stores are byte-identical math to R14 -> absmax
//     must stay 0.001953125),
//   - illu -> ILS[c][p] f32, SIL=132 (gate reads 2-way=free, f4 writes
//     conflict-free).
// R11's confounds fixed: stores keep R14's back-to-back half-line pairing
// (WRITE was exactly 64MB); T14 reg-prefetch of t+1 over the compute phase;
// 2 barriers/tile (convoy cost bounded ~8% by R9-vs-R14). LDS 67KB ->
// 2 blocks/CU, grid 512 persistent, TPB=4 (weights amortized 4x).

#define HW    65536
#define CHHW  (64 * 65536)
#define PT    128            // pixels per tile
#define SXT   68             // XT/WM/WP row stride (shorts): 136B, 8B-aligned
#define SIL   132            // ILS row stride (floats): 4 mod 32 dwords
#define WPX   32             // pixels per wave (compute window)
#define TPB   4              // tiles per block; grid = 2048/TPB = 512

typedef short s4_t __attribute__((ext_vector_type(4)));
typedef short s8_t __attribute__((ext_vector_type(8)));
typedef float f4_t __attribute__((ext_vector_type(4)));

static __device__ __forceinline__ unsigned short f2bf(float f) {
  unsigned u = __float_as_uint(f);
  return (unsigned short)((u + 0x7fffu + ((u >> 16) & 1u)) >> 16);  // RNE
}
static __device__ __forceinline__ s8_t ld8(const unsigned short* p) {
  s4_t lo = *(const s4_t*)p;        // rows 8B-aligned: 2x ds_read_b64
  s4_t hi = *(const s4_t*)(p + 4);
  s8_t r = {lo[0], lo[1], lo[2], lo[3], hi[0], hi[1], hi[2], hi[3]};
  return r;
}

__global__ __launch_bounds__(256, 2) void fused_hsattn(
    const float* __restrict__ x, const float* __restrict__ illu,
    const float* __restrict__ wvs, const float* __restrict__ wvt,
    const float* __restrict__ wproj, float* __restrict__ out) {
  __shared__ __align__(16) unsigned short WM[64 * SXT];   // 8.5 KB wmix
  __shared__ __align__(16) unsigned short WP[64 * SXT];   // 8.5 KB wproj
  __shared__ __align__(16) unsigned short XT[PT * SXT];   // 17.4 KB x^T/u'^T
  __shared__ __align__(16) float ILS[64 * SIL];           // 33.8 KB illu[c][p]

  const int tid  = threadIdx.x;
  const int lane = tid & 63;
  const int wv   = tid >> 6;
  const int n15  = lane & 15;
  const int q    = lane >> 4;
  const int wpx  = wv * WPX;               // wave's 32-px compute window

  // staging geometry: lane loads 4 consecutive px (16B) of one channel row;
  // a wave-inst covers 2 rows x 512B = 1KB contiguous (m13 copy pattern).
  const int srow = wv * 16 + (lane >> 5);  // +2*it -> wave stages 16 rows
  const int spx  = (lane & 31) * 4;

  // ---- (1) weight loads FIRST (oldest vmcnt slots; L2-hot after wave 1)
  f4_t wa[4], wb[4], wc[4];
#pragma unroll
  for (int it = 0; it < 4; ++it) {
    int j4 = (it * 256 + tid) * 4;
    wa[it] = *(const f4_t*)(wvs + j4);
    wb[it] = *(const f4_t*)(wvt + j4);
    wc[it] = *(const f4_t*)(wproj + j4);
  }

  // ---- (2) tile-0 loads -> regs (16B/lane, 1KB/inst)
  f4_t xg[8], ig[8];
  {
    const int g    = blockIdx.x * TPB;
    const int base = (g >> 9) * CHHW + ((g & 511) << 7);
#pragma unroll
    for (int it = 0; it < 8; ++it) {
      const int off = base + (srow + 2 * it) * HW + spx;
      xg[it] = *(const f4_t*)(x + off);
      ig[it] = *(const f4_t*)(illu + off);
    }
  }

  // ---- (3) convert + stage weights (once per block)
#pragma unroll
  for (int it = 0; it < 4; ++it) {
    int idx = it * 256 + tid;              // float4 index 0..1023
    int r = idx >> 4, c4 = (idx & 15) * 4;
    s4_t m, w;
#pragma unroll
    for (int j = 0; j < 4; ++j) {
      m[j] = (short)f2bf(0.6f * wa[it][j] + 0.4f * wb[it][j]);
      w[j] = (short)f2bf(wc[it][j]);
    }
    *(s4_t*)(WM + r * SXT + c4) = m;
    *(s4_t*)(WP + r * SXT + c4) = w;
  }

  // ---- (4) tile loop: stage -> S1 -> (prefetch t+1) compute+store -> S2
#pragma unroll
  for (int t = 0; t < TPB; ++t) {
    const int g    = blockIdx.x * TPB + t;
    const int base = (g >> 9) * CHHW + ((g & 511) << 7);

    // publish tile t from regs: x -> XT[p][c] bf16, illu -> ILS[c][p] f32
#pragma unroll
    for (int it = 0; it < 8; ++it) {
      const int r = srow + 2 * it;
      f4_t v = xg[it];
#pragma unroll
      for (int j = 0; j < 4; ++j)
        XT[(spx + j) * SXT + r] = f2bf(v[j]);
      *(f4_t*)(ILS + r * SIL + spx) = ig[it];
    }
    __syncthreads();                       // S1: tile t (and WM/WP) visible

    // T14: issue t+1 loads now; they fly over the whole compute phase
    if (t + 1 < TPB) {
      const int g2 = g + 1;
      const int b2 = (g2 >> 9) * CHHW + ((g2 & 511) << 7);
#pragma unroll
      for (int it = 0; it < 8; ++it) {
        const int off = b2 + (srow + 2 * it) * HW + spx;
        xg[it] = *(const f4_t*)(x + off);
        ig[it] = *(const f4_t*)(illu + off);
      }
    }

    // XH rows for this wave's two n-tiles (wave-private)
    unsigned short* xr0 = XT + (wpx + n15) * SXT;
    unsigned short* xr1 = XT + (wpx + 16 + n15) * SXT;

    // phase 1 + gate + u' write, n-tile 0 (reads own rows before writes)
    {
      f4_t acc[4];
#pragma unroll
      for (int i = 0; i < 4; ++i) acc[i] = (f4_t){0.f, 0.f, 0.f, 0.f};
#pragma unroll
      for (int kc = 0; kc < 2; ++kc) {
        s8_t B = ld8(xr0 + kc * 32 + q * 8);
#pragma unroll
        for (int mt = 0; mt < 4; ++mt) {
          s8_t A = ld8(WM + (mt * 16 + n15) * SXT + kc * 32 + q * 8);
          acc[mt] = __builtin_amdgcn_mfma_f32_16x16x32_bf16(A, B, acc[mt], 0, 0, 0);
        }
      }
#pragma unroll
      for (int mt = 0; mt < 4; ++mt) {
        s4_t h;
#pragma unroll
        for (int r = 0; r < 4; ++r) {
          const int c = mt * 16 + q * 4 + r;
          h[r] = (short)f2bf(acc[mt][r] * ILS[c * SIL + wpx + n15]);
        }
        *(s4_t*)(xr0 + mt * 16 + q * 4) = h;
      }
    }

    // phase 1 + gate + u' write, n-tile 1
    {
      f4_t acc[4];
#pragma unroll
      for (int i = 0; i < 4; ++i) acc[i] = (f4_t){0.f, 0.f, 0.f, 0.f};
#pragma unroll
      for (int kc = 0; kc < 2; ++kc) {
        s8_t B = ld8(xr1 + kc * 32 + q * 8);
#pragma unroll
        for (int mt = 0; mt < 4; ++mt) {
          s8_t A = ld8(WM + (mt * 16 + n15) * SXT + kc * 32 + q * 8);
          acc[mt] = __builtin_amdgcn_mfma_f32_16x16x32_bf16(A, B, acc[mt], 0, 0, 0);
        }
      }
#pragma unroll
      for (int mt = 0; mt < 4; ++mt) {
        s4_t h;
#pragma unroll
        for (int r = 0; r < 4; ++r) {
          const int c = mt * 16 + q * 4 + r;
          h[r] = (short)f2bf(acc[mt][r] * ILS[c * SIL + wpx + 16 + n15]);
        }
        *(s4_t*)(xr1 + mt * 16 + q * 4) = h;
      }
    }

    // phase 2 for both n-tiles (same-wave DS ordering vs the writes above)
    f4_t a20[4], a21[4];
#pragma unroll
    for (int i = 0; i < 4; ++i) {
      a20[i] = (f4_t){0.f, 0.f, 0.f, 0.f};
      a21[i] = (f4_t){0.f, 0.f, 0.f, 0.f};
    }
#pragma unroll
    for (int kc = 0; kc < 2; ++kc) {
      s8_t Bn0 = ld8(xr0 + kc * 32 + q * 8);
      s8_t Bn1 = ld8(xr1 + kc * 32 + q * 8);
#pragma unroll
      for (int mt = 0; mt < 4; ++mt) {
        s8_t A = ld8(WP + (mt * 16 + n15) * SXT + kc * 32 + q * 8);
        a20[mt] = __builtin_amdgcn_mfma_f32_16x16x32_bf16(A, Bn0, a20[mt], 0, 0, 0);
        a21[mt] = __builtin_amdgcn_mfma_f32_16x16x32_bf16(A, Bn1, a21[mt], 0, 0, 0);
      }
    }

    // stores: nt0/nt1 halves of each 128B line issued back-to-back (proven
    // clean in R14: WRITE == exactly output size)
#pragma unroll
    for (int mt = 0; mt < 4; ++mt) {
      float* op = out + base + (mt * 16 + q * 4) * HW + wpx + n15;
#pragma unroll
      for (int r = 0; r < 4; ++r) {
        op[r * HW]      = a20[mt][r];
        op[r * HW + 16] = a21[mt][r];
      }
    }
    __syncthreads();                       // S2: safe to restage XT/ILS
  }
}

extern "C" void kernel_launch(void* const* d_in, const int* in_sizes, int n_in,
                              void* d_out, int out_size, void* d_ws, size_t ws_size,
                              hipStream_t stream) {
  const float* x     = (const float*)d_in[0];   // (4,64,256,256)
  const float* illu  = (const float*)d_in[1];   // (4,64,256,256)
  const float* wvs   = (const float*)d_in[4];   // w_v_spec (64,64)
  const float* wvt   = (const float*)d_in[7];   // w_v_spat (64,64)
  const float* wproj = (const float*)d_in[10];  // w_proj   (64,64)
  float* out = (float*)d_out;

  // 2048 tiles (512 per image x 4 images) / TPB = 512 blocks, 2 per CU
  fused_hsattn<<<(4 * (HW / PT)) / TPB, 256, 0, stream>>>(x, illu, wvs, wvt,
                                                          wproj, out);
}